// Round 5
// baseline (1406.877 us; speedup 1.0000x reference)
//
#include <hip/hip_runtime.h>

// NodeDenoisingADMM: N=20000, FEAT=64, K=4, NNZ=320000, NU=2.0, GAMMA=1.0, J=3
// 14 scan iterations, output = final U (N,FEAT) fp32.
//
// State reduction (GAMMA=1): carried state is v alone.
//   S_t = W_k @ U_t ; Y_t = S_t + v_{t-1} ; Z_t = soft(S_t + Y_t, nu_k d)
//   v_t = Y_t - Z_t ; U_{t+1} = (dm*F - sum_k W_k v_k)/(dm+1), dm = d*mask^2
//
// spmm: wave per R contiguous CSR rows (R=10/4) — few large blocks instead of
// 20000 tiny ones (round-4 profile showed 8% occupancy = WG-launch-rate bound).
// Row offsets preloaded lane-parallel once per wave, broadcast via __shfl.
// Edge meta for a 64-edge chunk loaded lane-parallel, broadcast via __shfl.
// lane = 16*sub_edge + quad; 4 sub-edges gather 256B X rows as float4s;
// shfl_xor(16,32) butterfly reduces the 4 sub-accumulators.

constexpr int N_    = 20000;
constexpr int FEAT_ = 64;
constexpr int K_    = 4;
constexpr int NNZ_  = 320000;
constexpr int NF    = N_ * FEAT_;     // 1,280,000
constexpr int KN    = K_ * N_;        // 80,000 CSR rows
constexpr int NEDGE = K_ * NNZ_;      // 1,280,000
constexpr int NITER = 14;
constexpr int BLK   = 256;
constexpr int NSB   = (KN + 255) / 256;  // 313 scan blocks

constexpr int R_SP  = 10;                          // rows/wave, spmm
constexpr int NB_SP = ((KN + R_SP - 1) / R_SP + 3) / 4;   // 2000 blocks
constexpr int R_WT  = 4;                           // rows/wave, wtv
constexpr int NB_WT = ((N_ + R_WT - 1) / R_WT + 3) / 4;   // 1250 blocks

__constant__ float c_nu[4] = {0.0f, 2.0f, 0.5f, 0.125f};

__device__ __forceinline__ float softf(float x, float t) {
    float a = fabsf(x) - t;
    a = a > 0.0f ? a : 0.0f;
    return copysignf(a, x);
}

// ---------------- CSR build ----------------

__global__ __launch_bounds__(BLK) void precompute_kernel(
    const float* __restrict__ d, const float* __restrict__ mask,
    float* __restrict__ dm) {
    int n = blockIdx.x * BLK + threadIdx.x;
    if (n >= N_) return;
    dm[n] = d[n] * mask[n] * mask[n];
}

__global__ __launch_bounds__(BLK) void hist_kernel(
    const int* __restrict__ rows, int* __restrict__ cnt) {
    int e = blockIdx.x * BLK + threadIdx.x;
    if (e >= NEDGE) return;
    int k = e / NNZ_;
    atomicAdd(&cnt[k * N_ + rows[e]], 1);
}

// block-local exclusive scan (256/block) + block sums
__global__ __launch_bounds__(256) void scan1_kernel(
    const int* __restrict__ cnt, int* __restrict__ loc,
    int* __restrict__ bsum) {
    int i = blockIdx.x * 256 + threadIdx.x;
    int x = (i < KN) ? cnt[i] : 0;
    int lane = threadIdx.x & 63, wid = threadIdx.x >> 6;
    int v = x;
    #pragma unroll
    for (int off = 1; off < 64; off <<= 1) {
        int t = __shfl_up(v, off, 64);
        if (lane >= off) v += t;
    }
    __shared__ int ws[4];
    if (lane == 63) ws[wid] = v;
    __syncthreads();
    int add = 0;
    for (int u = 0; u < wid; ++u) add += ws[u];
    v += add;
    if (i < KN) loc[i] = v - x;
    if (threadIdx.x == 255) bsum[blockIdx.x] = v;
}

// single-block exclusive scan of the 313 block sums
__global__ __launch_bounds__(512) void scan2_kernel(int* __restrict__ bsum) {
    int tid = threadIdx.x;
    int x = (tid < NSB) ? bsum[tid] : 0;
    int lane = tid & 63, wid = tid >> 6;
    int v = x;
    #pragma unroll
    for (int off = 1; off < 64; off <<= 1) {
        int t = __shfl_up(v, off, 64);
        if (lane >= off) v += t;
    }
    __shared__ int ws[8];
    if (lane == 63) ws[wid] = v;
    __syncthreads();
    int add = 0;
    for (int u = 0; u < wid; ++u) add += ws[u];
    v += add;
    if (tid < NSB) bsum[tid] = v - x;
}

// offs/cursor = loc + bsum[block]; offs[KN] = NEDGE
__global__ __launch_bounds__(256) void scan3_kernel(
    const int* __restrict__ loc, const int* __restrict__ bsum,
    int* __restrict__ offs, int* __restrict__ cursor) {
    int i = blockIdx.x * 256 + threadIdx.x;
    if (i < KN) {
        int v = loc[i] + bsum[blockIdx.x];
        offs[i] = v;
        cursor[i] = v;
    }
    if (i == 0) offs[KN] = NEDGE;
}

// scatter only the permutation (4B random writes)
__global__ __launch_bounds__(BLK) void scatter_perm_kernel(
    const int* __restrict__ rows, int* __restrict__ cursor,
    int* __restrict__ perm) {
    int e = blockIdx.x * BLK + threadIdx.x;
    if (e >= NEDGE) return;
    int k = e / NNZ_;
    int pos = atomicAdd(&cursor[k * N_ + rows[e]], 1);
    perm[pos] = e;
}

// coalesced-write build: ccol/cval[pos] = cols/vals[perm[pos]]
__global__ __launch_bounds__(BLK) void build_kernel(
    const int* __restrict__ perm, const int* __restrict__ cols,
    const float* __restrict__ vals, int* __restrict__ ccol,
    float* __restrict__ cval) {
    int pos = blockIdx.x * BLK + threadIdx.x;
    if (pos >= NEDGE) return;
    int e = perm[pos];
    ccol[pos] = cols[e];
    cval[pos] = vals[e];
}

// ---------------- iteration kernels ----------------

// Accumulate one CSR row [beg,end) into acc (float4/lane, sub-edge parallel).
// Meta for up to 64 edges loaded lane-parallel, broadcast via __shfl.
__device__ __forceinline__ void row_accum(
    const int* __restrict__ ccol, const float* __restrict__ cval,
    const float4* __restrict__ X4, int beg, int end, int lane, int sub,
    int q, float4& acc) {
    for (int ebase = beg; ebase < end; ebase += 64) {
        int n = end - ebase;             // wave-uniform
        if (n > 64) n = 64;
        int   c_l = 0;
        float v_l = 0.0f;
        if (lane < n) {
            c_l = ccol[ebase + lane];
            v_l = cval[ebase + lane];
        }
        int iters = (n + 3) >> 2;
        #pragma unroll 2
        for (int it = 0; it < iters; ++it) {
            int j = 4 * it + sub;        // lanes >= n hold c=0,v=0
            int   c = __shfl(c_l, j, 64);
            float v = __shfl(v_l, j, 64);
            float4 x = X4[c * (FEAT_ / 4) + q];
            acc.x += v * x.x; acc.y += v * x.y;
            acc.z += v * x.z; acc.w += v * x.w;
        }
    }
}

__device__ __forceinline__ void butterfly4(float4& a) {
    #pragma unroll
    for (int m = 16; m <= 32; m <<= 1) {
        a.x += __shfl_xor(a.x, m, 64);
        a.y += __shfl_xor(a.y, m, 64);
        a.z += __shfl_xor(a.z, m, 64);
        a.w += __shfl_xor(a.w, m, 64);
    }
}

// wave per R_SP contiguous (k,row) CSR rows; fused v-update. FIRST: Y=0, X=F.
template <bool FIRST>
__global__ __launch_bounds__(BLK) void spmm_fused_kernel(
    const int* __restrict__ offs, const int* __restrict__ ccol,
    const float* __restrict__ cval, const float* __restrict__ X,
    const float* __restrict__ d, float* __restrict__ V) {
    int wave = (blockIdx.x * BLK + threadIdx.x) >> 6;
    int lane = threadIdx.x & 63;
    int sub  = lane >> 4, q = lane & 15;
    int base = wave * R_SP;
    if (base >= KN) return;
    int off_l = 0;
    if (lane <= R_SP) {
        int i = base + lane;
        if (i > KN) i = KN;
        off_l = offs[i];
    }
    const float4* X4 = (const float4*)X;
    float4* V4 = (float4*)V;
    for (int r = 0; r < R_SP; ++r) {
        int w = base + r;
        if (w >= KN) break;
        int beg = __shfl(off_l, r, 64);
        int end = __shfl(off_l, r + 1, 64);
        float4 acc = {0.f, 0.f, 0.f, 0.f};
        row_accum(ccol, cval, X4, beg, end, lane, sub, q, acc);
        butterfly4(acc);                 // all lanes hold row sums
        if (sub == 0) {
            int k   = w / N_;
            int row = w - k * N_;
            int idx4 = w * (FEAT_ / 4) + q;
            float thr = c_nu[k] * d[row];
            float4 y;
            if (FIRST) {
                y = make_float4(0.f, 0.f, 0.f, 0.f);
            } else {
                float4 vp = V4[idx4];    // v_{t-1}
                y.x = acc.x + vp.x; y.y = acc.y + vp.y;
                y.z = acc.z + vp.z; y.w = acc.w + vp.w;
            }
            float4 o;
            o.x = y.x - softf(acc.x + y.x, thr);
            o.y = y.y - softf(acc.y + y.y, thr);
            o.z = y.z - softf(acc.z + y.z, thr);
            o.w = y.w - softf(acc.w + y.w, thr);
            V4[idx4] = o;                // v_t
        }
    }
}

// wave per R_WT contiguous node rows: acc = sum_k (W_k @ v_k)[row];
// U = (dm*F - acc)/(dm+1)
__global__ __launch_bounds__(BLK) void wtv_u_kernel(
    const int* __restrict__ offs, const int* __restrict__ ccol,
    const float* __restrict__ cval, const float* __restrict__ V,
    const float* __restrict__ F, const float* __restrict__ dm,
    float* __restrict__ U) {
    int wave = (blockIdx.x * BLK + threadIdx.x) >> 6;
    int lane = threadIdx.x & 63;
    int sub  = lane >> 4, q = lane & 15;
    int base = wave * R_WT;
    if (base >= N_) return;
    int off_l[K_];
    #pragma unroll
    for (int k = 0; k < K_; ++k) {
        int i = base + lane;
        if (i > N_) i = N_;
        off_l[k] = (lane <= R_WT) ? offs[k * N_ + i] : 0;
    }
    for (int r = 0; r < R_WT; ++r) {
        int w = base + r;
        if (w >= N_) break;
        float4 acc = {0.f, 0.f, 0.f, 0.f};
        #pragma unroll
        for (int k = 0; k < K_; ++k) {
            int beg = __shfl(off_l[k], r, 64);
            int end = __shfl(off_l[k], r + 1, 64);
            row_accum(ccol, cval, (const float4*)(V + (size_t)k * NF),
                      beg, end, lane, sub, q, acc);
        }
        butterfly4(acc);
        if (sub == 0) {
            int idx4 = w * (FEAT_ / 4) + q;
            float dmv = dm[w];
            float r2 = 1.0f / (dmv + 1.0f);
            float4 f = ((const float4*)F)[idx4];
            float4 o;
            o.x = (dmv * f.x - acc.x) * r2; o.y = (dmv * f.y - acc.y) * r2;
            o.z = (dmv * f.z - acc.z) * r2; o.w = (dmv * f.w - acc.w) * r2;
            ((float4*)U)[idx4] = o;
        }
    }
}

extern "C" void kernel_launch(void* const* d_in, const int* in_sizes, int n_in,
                              void* d_out, int out_size, void* d_ws, size_t ws_size,
                              hipStream_t stream) {
    const float* F      = (const float*)d_in[0];
    const int*   w_rows = (const int*)d_in[1];
    const int*   w_cols = (const int*)d_in[2];
    const float* w_vals = (const float*)d_in[3];
    const float* d      = (const float*)d_in[4];
    const float* mask   = (const float*)d_in[5];
    float* U = (float*)d_out;

    // workspace layout (~38 MB)
    float* V      = (float*)d_ws;                 // 5,120,000 f
    float* dm     = V + (size_t)NF * K_;          // N
    int*   cnt    = (int*)(dm + N_);              // KN
    int*   loc    = cnt + KN;                     // KN
    int*   bsum   = loc + KN;                     // pad 512
    int*   offs   = bsum + 512;                   // KN+1
    int*   cursor = offs + KN + 1;                // KN
    int*   perm   = cursor + KN;                  // NEDGE
    int*   ccol   = perm + NEDGE;                 // NEDGE
    float* cval   = (float*)(ccol + NEDGE);       // NEDGE

    const int gEdge = NEDGE / BLK;                // 5000
    const int gN    = (N_ + BLK - 1) / BLK;

    // ---- CSR build ----
    hipMemsetAsync(cnt, 0, (size_t)KN * 4, stream);
    precompute_kernel<<<gN, BLK, 0, stream>>>(d, mask, dm);
    hist_kernel<<<gEdge, BLK, 0, stream>>>(w_rows, cnt);
    scan1_kernel<<<NSB, 256, 0, stream>>>(cnt, loc, bsum);
    scan2_kernel<<<1, 512, 0, stream>>>(bsum);
    scan3_kernel<<<NSB, 256, 0, stream>>>(loc, bsum, offs, cursor);
    scatter_perm_kernel<<<gEdge, BLK, 0, stream>>>(w_rows, cursor, perm);
    build_kernel<<<gEdge, BLK, 0, stream>>>(perm, w_cols, w_vals, ccol, cval);

    // ---- iterations ----
    spmm_fused_kernel<true><<<NB_SP, BLK, 0, stream>>>(offs, ccol, cval, F, d, V);
    for (int it = 0; it < NITER; ++it) {
        wtv_u_kernel<<<NB_WT, BLK, 0, stream>>>(offs, ccol, cval, V, F, dm, U);
        if (it < NITER - 1)
            spmm_fused_kernel<false><<<NB_SP, BLK, 0, stream>>>(offs, ccol, cval,
                                                                U, d, V);
    }
}

// Round 6
// 1300.149 us; speedup vs baseline: 1.0821x; 1.0821x over previous
//
#include <hip/hip_runtime.h>

// NodeDenoisingADMM: N=20000, FEAT=64, K=4, NNZ=320000, NU=2.0, GAMMA=1.0, J=3
// 14 scan iterations, output = final U (N,FEAT) fp32.
//
// State reduction (GAMMA=1): carried state is v alone.
//   S_t = W_k @ U_t ; Y_t = S_t + v_{t-1} ; Z_t = soft(S_t + Y_t, nu_k d)
//   v_t = Y_t - Z_t ; U_{t+1} = (dm*F - sum_k W_k v_k)/(dm+1), dm = d*mask^2
//
// R5 profile: gather arrays are re-fetched by each of the 8 non-coherent XCD
// L2s (wtv FETCH=127MB for a 20.5MB V) -> HBM-BW-bound. Fix: gather operands
// (U, V, F) kept as bf16 side copies written in the epilogues. U_bf = 2.56MB
// fits a single XCD L2; V_bf halves the duplicated traffic. Accumulation and
// the carried recurrence stay fp32.

constexpr int N_    = 20000;
constexpr int FEAT_ = 64;
constexpr int K_    = 4;
constexpr int NNZ_  = 320000;
constexpr int NF    = N_ * FEAT_;     // 1,280,000
constexpr int KN    = K_ * N_;        // 80,000 CSR rows
constexpr int NEDGE = K_ * NNZ_;      // 1,280,000
constexpr int NITER = 14;
constexpr int BLK   = 256;
constexpr int NSB   = (KN + 255) / 256;  // 313 scan blocks

constexpr int R_SP  = 10;                          // rows/wave, spmm
constexpr int NB_SP = ((KN + R_SP - 1) / R_SP + 3) / 4;   // 2000 blocks
constexpr int R_WT  = 4;                           // rows/wave, wtv
constexpr int NB_WT = ((N_ + R_WT - 1) / R_WT + 3) / 4;   // 1250 blocks

__constant__ float c_nu[4] = {0.0f, 2.0f, 0.5f, 0.125f};

__device__ __forceinline__ float softf(float x, float t) {
    float a = fabsf(x) - t;
    a = a > 0.0f ? a : 0.0f;
    return copysignf(a, x);
}

__device__ __forceinline__ float bf2f(unsigned short u) {
    union { unsigned int i; float f; } x;
    x.i = ((unsigned int)u) << 16;
    return x.f;
}
__device__ __forceinline__ unsigned short f2bf(float f) {   // RNE
    union { float f; unsigned int i; } x;
    x.f = f;
    unsigned int r = x.i + 0x7FFFu + ((x.i >> 16) & 1u);
    return (unsigned short)(r >> 16);
}

// ---------------- CSR build + precompute ----------------

// dm[n] = d*mask^2 ; F_bf = bf16(F)
__global__ __launch_bounds__(BLK) void precompute_kernel(
    const float* __restrict__ F, const float* __restrict__ d,
    const float* __restrict__ mask, float* __restrict__ dm,
    unsigned short* __restrict__ F_bf) {
    int i = blockIdx.x * BLK + threadIdx.x;       // over NF/4
    if (i >= NF / 4) return;
    float4 f = ((const float4*)F)[i];
    ushort4 o;
    o.x = f2bf(f.x); o.y = f2bf(f.y); o.z = f2bf(f.z); o.w = f2bf(f.w);
    ((ushort4*)F_bf)[i] = o;
    if ((i & (FEAT_ / 4 - 1)) == 0) {
        int n = i / (FEAT_ / 4);
        dm[n] = d[n] * mask[n] * mask[n];
    }
}

__global__ __launch_bounds__(BLK) void hist_kernel(
    const int* __restrict__ rows, int* __restrict__ cnt) {
    int e = blockIdx.x * BLK + threadIdx.x;
    if (e >= NEDGE) return;
    int k = e / NNZ_;
    atomicAdd(&cnt[k * N_ + rows[e]], 1);
}

__global__ __launch_bounds__(256) void scan1_kernel(
    const int* __restrict__ cnt, int* __restrict__ loc,
    int* __restrict__ bsum) {
    int i = blockIdx.x * 256 + threadIdx.x;
    int x = (i < KN) ? cnt[i] : 0;
    int lane = threadIdx.x & 63, wid = threadIdx.x >> 6;
    int v = x;
    #pragma unroll
    for (int off = 1; off < 64; off <<= 1) {
        int t = __shfl_up(v, off, 64);
        if (lane >= off) v += t;
    }
    __shared__ int ws[4];
    if (lane == 63) ws[wid] = v;
    __syncthreads();
    int add = 0;
    for (int u = 0; u < wid; ++u) add += ws[u];
    v += add;
    if (i < KN) loc[i] = v - x;
    if (threadIdx.x == 255) bsum[blockIdx.x] = v;
}

__global__ __launch_bounds__(512) void scan2_kernel(int* __restrict__ bsum) {
    int tid = threadIdx.x;
    int x = (tid < NSB) ? bsum[tid] : 0;
    int lane = tid & 63, wid = tid >> 6;
    int v = x;
    #pragma unroll
    for (int off = 1; off < 64; off <<= 1) {
        int t = __shfl_up(v, off, 64);
        if (lane >= off) v += t;
    }
    __shared__ int ws[8];
    if (lane == 63) ws[wid] = v;
    __syncthreads();
    int add = 0;
    for (int u = 0; u < wid; ++u) add += ws[u];
    v += add;
    if (tid < NSB) bsum[tid] = v - x;
}

__global__ __launch_bounds__(256) void scan3_kernel(
    const int* __restrict__ loc, const int* __restrict__ bsum,
    int* __restrict__ offs, int* __restrict__ cursor) {
    int i = blockIdx.x * 256 + threadIdx.x;
    if (i < KN) {
        int v = loc[i] + bsum[blockIdx.x];
        offs[i] = v;
        cursor[i] = v;
    }
    if (i == 0) offs[KN] = NEDGE;
}

__global__ __launch_bounds__(BLK) void scatter_perm_kernel(
    const int* __restrict__ rows, int* __restrict__ cursor,
    int* __restrict__ perm) {
    int e = blockIdx.x * BLK + threadIdx.x;
    if (e >= NEDGE) return;
    int k = e / NNZ_;
    int pos = atomicAdd(&cursor[k * N_ + rows[e]], 1);
    perm[pos] = e;
}

__global__ __launch_bounds__(BLK) void build_kernel(
    const int* __restrict__ perm, const int* __restrict__ cols,
    const float* __restrict__ vals, int* __restrict__ ccol,
    float* __restrict__ cval) {
    int pos = blockIdx.x * BLK + threadIdx.x;
    if (pos >= NEDGE) return;
    int e = perm[pos];
    ccol[pos] = cols[e];
    cval[pos] = vals[e];
}

// ---------------- iteration kernels ----------------

// Accumulate one CSR row [beg,end): bf16 gather (ushort4 = 4 feats/lane,
// 128B/row), fp32 FMA. Edge meta loaded lane-parallel, broadcast via __shfl.
__device__ __forceinline__ void row_accum_bf(
    const int* __restrict__ ccol, const float* __restrict__ cval,
    const ushort4* __restrict__ Xb, int beg, int end, int lane, int sub,
    int q, float4& acc) {
    for (int ebase = beg; ebase < end; ebase += 64) {
        int n = end - ebase;             // wave-uniform
        if (n > 64) n = 64;
        int   c_l = 0;
        float v_l = 0.0f;
        if (lane < n) {
            c_l = ccol[ebase + lane];
            v_l = cval[ebase + lane];
        }
        int iters = (n + 3) >> 2;
        #pragma unroll 2
        for (int it = 0; it < iters; ++it) {
            int j = 4 * it + sub;        // lanes >= n hold c=0,v=0
            int   c = __shfl(c_l, j, 64);
            float v = __shfl(v_l, j, 64);
            ushort4 x = Xb[c * (FEAT_ / 4) + q];
            acc.x += v * bf2f(x.x); acc.y += v * bf2f(x.y);
            acc.z += v * bf2f(x.z); acc.w += v * bf2f(x.w);
        }
    }
}

__device__ __forceinline__ void butterfly4(float4& a) {
    #pragma unroll
    for (int m = 16; m <= 32; m <<= 1) {
        a.x += __shfl_xor(a.x, m, 64);
        a.y += __shfl_xor(a.y, m, 64);
        a.z += __shfl_xor(a.z, m, 64);
        a.w += __shfl_xor(a.w, m, 64);
    }
}

// wave per R_SP contiguous (k,row) CSR rows; acc = (W_k @ X)[row]; fused
// v-update entirely in bf16 state V_bf. FIRST: Y=0, X=F_bf.
template <bool FIRST>
__global__ __launch_bounds__(BLK) void spmm_fused_kernel(
    const int* __restrict__ offs, const int* __restrict__ ccol,
    const float* __restrict__ cval, const unsigned short* __restrict__ Xb,
    const float* __restrict__ d, unsigned short* __restrict__ V_bf) {
    int wave = (blockIdx.x * BLK + threadIdx.x) >> 6;
    int lane = threadIdx.x & 63;
    int sub  = lane >> 4, q = lane & 15;
    int base = wave * R_SP;
    if (base >= KN) return;
    int off_l = 0;
    if (lane <= R_SP) {
        int i = base + lane;
        if (i > KN) i = KN;
        off_l = offs[i];
    }
    const ushort4* X4 = (const ushort4*)Xb;
    ushort4* V4 = (ushort4*)V_bf;
    for (int r = 0; r < R_SP; ++r) {
        int w = base + r;
        if (w >= KN) break;
        int beg = __shfl(off_l, r, 64);
        int end = __shfl(off_l, r + 1, 64);
        float4 acc = {0.f, 0.f, 0.f, 0.f};
        row_accum_bf(ccol, cval, X4, beg, end, lane, sub, q, acc);
        butterfly4(acc);                 // all lanes hold row sums
        if (sub == 0) {
            int k   = w / N_;
            int row = w - k * N_;
            int idx4 = w * (FEAT_ / 4) + q;
            float thr = c_nu[k] * d[row];
            float4 y;
            if (FIRST) {
                y = make_float4(0.f, 0.f, 0.f, 0.f);
            } else {
                ushort4 vp = V4[idx4];   // v_{t-1} (bf16 state)
                y.x = acc.x + bf2f(vp.x); y.y = acc.y + bf2f(vp.y);
                y.z = acc.z + bf2f(vp.z); y.w = acc.w + bf2f(vp.w);
            }
            ushort4 o;
            o.x = f2bf(y.x - softf(acc.x + y.x, thr));
            o.y = f2bf(y.y - softf(acc.y + y.y, thr));
            o.z = f2bf(y.z - softf(acc.z + y.z, thr));
            o.w = f2bf(y.w - softf(acc.w + y.w, thr));
            V4[idx4] = o;                // v_t
        }
    }
}

// wave per R_WT contiguous node rows: acc = sum_k (W_k @ v_k)[row];
// U = (dm*F - acc)/(dm+1), stored fp32 (d_out) + bf16 (gather copy)
__global__ __launch_bounds__(BLK) void wtv_u_kernel(
    const int* __restrict__ offs, const int* __restrict__ ccol,
    const float* __restrict__ cval, const unsigned short* __restrict__ V_bf,
    const float* __restrict__ F, const float* __restrict__ dm,
    float* __restrict__ U, unsigned short* __restrict__ U_bf) {
    int wave = (blockIdx.x * BLK + threadIdx.x) >> 6;
    int lane = threadIdx.x & 63;
    int sub  = lane >> 4, q = lane & 15;
    int base = wave * R_WT;
    if (base >= N_) return;
    int off_l[K_];
    #pragma unroll
    for (int k = 0; k < K_; ++k) {
        int i = base + lane;
        if (i > N_) i = N_;
        off_l[k] = (lane <= R_WT) ? offs[k * N_ + i] : 0;
    }
    for (int r = 0; r < R_WT; ++r) {
        int w = base + r;
        if (w >= N_) break;
        float4 acc = {0.f, 0.f, 0.f, 0.f};
        #pragma unroll
        for (int k = 0; k < K_; ++k) {
            int beg = __shfl(off_l[k], r, 64);
            int end = __shfl(off_l[k], r + 1, 64);
            row_accum_bf(ccol, cval,
                         (const ushort4*)(V_bf + (size_t)k * NF),
                         beg, end, lane, sub, q, acc);
        }
        butterfly4(acc);
        if (sub == 0) {
            int idx4 = w * (FEAT_ / 4) + q;
            float dmv = dm[w];
            float r2 = 1.0f / (dmv + 1.0f);
            float4 f = ((const float4*)F)[idx4];
            float4 o;
            o.x = (dmv * f.x - acc.x) * r2; o.y = (dmv * f.y - acc.y) * r2;
            o.z = (dmv * f.z - acc.z) * r2; o.w = (dmv * f.w - acc.w) * r2;
            ((float4*)U)[idx4] = o;
            ushort4 ob;
            ob.x = f2bf(o.x); ob.y = f2bf(o.y);
            ob.z = f2bf(o.z); ob.w = f2bf(o.w);
            ((ushort4*)U_bf)[idx4] = ob;
        }
    }
}

extern "C" void kernel_launch(void* const* d_in, const int* in_sizes, int n_in,
                              void* d_out, int out_size, void* d_ws, size_t ws_size,
                              hipStream_t stream) {
    const float* F      = (const float*)d_in[0];
    const int*   w_rows = (const int*)d_in[1];
    const int*   w_cols = (const int*)d_in[2];
    const float* w_vals = (const float*)d_in[3];
    const float* d      = (const float*)d_in[4];
    const float* mask   = (const float*)d_in[5];
    float* U = (float*)d_out;

    // workspace layout (~33 MB)
    unsigned short* V_bf = (unsigned short*)d_ws;          // KN*FEAT us
    unsigned short* U_bf = V_bf + (size_t)KN * FEAT_;      // NF us
    unsigned short* F_bf = U_bf + NF;                      // NF us
    float* dm     = (float*)(F_bf + NF);                   // N
    int*   cnt    = (int*)(dm + N_);                       // KN
    int*   loc    = cnt + KN;                              // KN
    int*   bsum   = loc + KN;                              // pad 512
    int*   offs   = bsum + 512;                            // KN+1
    int*   cursor = offs + KN + 1;                         // KN
    int*   perm   = cursor + KN;                           // NEDGE
    int*   ccol   = perm + NEDGE;                          // NEDGE
    float* cval   = (float*)(ccol + NEDGE);                // NEDGE

    const int gEdge = NEDGE / BLK;                // 5000
    const int gNF4  = (NF / 4) / BLK;             // 1250

    // ---- CSR build + precompute ----
    hipMemsetAsync(cnt, 0, (size_t)KN * 4, stream);
    precompute_kernel<<<gNF4, BLK, 0, stream>>>(F, d, mask, dm, F_bf);
    hist_kernel<<<gEdge, BLK, 0, stream>>>(w_rows, cnt);
    scan1_kernel<<<NSB, 256, 0, stream>>>(cnt, loc, bsum);
    scan2_kernel<<<1, 512, 0, stream>>>(bsum);
    scan3_kernel<<<NSB, 256, 0, stream>>>(loc, bsum, offs, cursor);
    scatter_perm_kernel<<<gEdge, BLK, 0, stream>>>(w_rows, cursor, perm);
    build_kernel<<<gEdge, BLK, 0, stream>>>(perm, w_cols, w_vals, ccol, cval);

    // ---- iterations ----
    spmm_fused_kernel<true><<<NB_SP, BLK, 0, stream>>>(offs, ccol, cval,
                                                       F_bf, d, V_bf);
    for (int it = 0; it < NITER; ++it) {
        wtv_u_kernel<<<NB_WT, BLK, 0, stream>>>(offs, ccol, cval, V_bf,
                                                F, dm, U, U_bf);
        if (it < NITER - 1)
            spmm_fused_kernel<false><<<NB_SP, BLK, 0, stream>>>(offs, ccol, cval,
                                                                U_bf, d, V_bf);
    }
}

// Round 7
// 1052.173 us; speedup vs baseline: 1.3371x; 1.2357x over previous
//
#include <hip/hip_runtime.h>

// NodeDenoisingADMM: N=20000, FEAT=64, K=4, NNZ=320000, NU=2.0, GAMMA=1.0, J=3
// 14 scan iterations, output = final U (N,FEAT) fp32.
//
// State reduction (GAMMA=1): carried state is v alone.
//   S_t = W_k @ U_t ; Y_t = S_t + v_{t-1} ; Z_t = soft(S_t + Y_t, nu_k d)
//   v_t = Y_t - Z_t ; U_{t+1} = (dm*F - sum_k W_k v_k)/(dm+1), dm = d*mask^2
//
// Gather operands (U,V,F) are bf16 side copies (halves XCD-duplicated HBM
// traffic). Edge meta packed as int2{col, val_bits} - one 8B load/store.
// row_accum issues 4 batched gathers per wave-iter (padded with zero-lanes)
// for 4x memory-level parallelism.

constexpr int N_    = 20000;
constexpr int FEAT_ = 64;
constexpr int K_    = 4;
constexpr int NNZ_  = 320000;
constexpr int NF    = N_ * FEAT_;     // 1,280,000
constexpr int KN    = K_ * N_;        // 80,000 CSR rows
constexpr int NEDGE = K_ * NNZ_;      // 1,280,000
constexpr int NITER = 14;
constexpr int BLK   = 256;
constexpr int NSB   = (KN + 255) / 256;  // 313 scan blocks

constexpr int R_SP  = 10;                          // rows/wave, spmm
constexpr int NB_SP = ((KN + R_SP - 1) / R_SP + 3) / 4;   // 2000 blocks
constexpr int R_WT  = 2;                           // rows/wave, wtv
constexpr int NB_WT = ((N_ + R_WT - 1) / R_WT + 3) / 4;   // 2500 blocks

__constant__ float c_nu[4] = {0.0f, 2.0f, 0.5f, 0.125f};

__device__ __forceinline__ float softf(float x, float t) {
    float a = fabsf(x) - t;
    a = a > 0.0f ? a : 0.0f;
    return copysignf(a, x);
}

__device__ __forceinline__ float bf2f(unsigned short u) {
    union { unsigned int i; float f; } x;
    x.i = ((unsigned int)u) << 16;
    return x.f;
}
__device__ __forceinline__ unsigned short f2bf(float f) {   // RNE
    union { float f; unsigned int i; } x;
    x.f = f;
    unsigned int r = x.i + 0x7FFFu + ((x.i >> 16) & 1u);
    return (unsigned short)(r >> 16);
}

// ---------------- CSR build + precompute ----------------

// dm[n] = d*mask^2 ; F_bf = bf16(F)
__global__ __launch_bounds__(BLK) void precompute_kernel(
    const float* __restrict__ F, const float* __restrict__ d,
    const float* __restrict__ mask, float* __restrict__ dm,
    unsigned short* __restrict__ F_bf) {
    int i = blockIdx.x * BLK + threadIdx.x;       // over NF/4
    if (i >= NF / 4) return;
    float4 f = ((const float4*)F)[i];
    ushort4 o;
    o.x = f2bf(f.x); o.y = f2bf(f.y); o.z = f2bf(f.z); o.w = f2bf(f.w);
    ((ushort4*)F_bf)[i] = o;
    if ((i & (FEAT_ / 4 - 1)) == 0) {
        int n = i / (FEAT_ / 4);
        dm[n] = d[n] * mask[n] * mask[n];
    }
}

__global__ __launch_bounds__(BLK) void hist_kernel(
    const int* __restrict__ rows, int* __restrict__ cnt) {
    int e = blockIdx.x * BLK + threadIdx.x;
    if (e >= NEDGE) return;
    int k = e / NNZ_;
    atomicAdd(&cnt[k * N_ + rows[e]], 1);
}

__global__ __launch_bounds__(256) void scan1_kernel(
    const int* __restrict__ cnt, int* __restrict__ loc,
    int* __restrict__ bsum) {
    int i = blockIdx.x * 256 + threadIdx.x;
    int x = (i < KN) ? cnt[i] : 0;
    int lane = threadIdx.x & 63, wid = threadIdx.x >> 6;
    int v = x;
    #pragma unroll
    for (int off = 1; off < 64; off <<= 1) {
        int t = __shfl_up(v, off, 64);
        if (lane >= off) v += t;
    }
    __shared__ int ws[4];
    if (lane == 63) ws[wid] = v;
    __syncthreads();
    int add = 0;
    for (int u = 0; u < wid; ++u) add += ws[u];
    v += add;
    if (i < KN) loc[i] = v - x;
    if (threadIdx.x == 255) bsum[blockIdx.x] = v;
}

__global__ __launch_bounds__(512) void scan2_kernel(int* __restrict__ bsum) {
    int tid = threadIdx.x;
    int x = (tid < NSB) ? bsum[tid] : 0;
    int lane = tid & 63, wid = tid >> 6;
    int v = x;
    #pragma unroll
    for (int off = 1; off < 64; off <<= 1) {
        int t = __shfl_up(v, off, 64);
        if (lane >= off) v += t;
    }
    __shared__ int ws[8];
    if (lane == 63) ws[wid] = v;
    __syncthreads();
    int add = 0;
    for (int u = 0; u < wid; ++u) add += ws[u];
    v += add;
    if (tid < NSB) bsum[tid] = v - x;
}

__global__ __launch_bounds__(256) void scan3_kernel(
    const int* __restrict__ loc, const int* __restrict__ bsum,
    int* __restrict__ offs, int* __restrict__ cursor) {
    int i = blockIdx.x * 256 + threadIdx.x;
    if (i < KN) {
        int v = loc[i] + bsum[blockIdx.x];
        offs[i] = v;
        cursor[i] = v;
    }
    if (i == 0) offs[KN] = NEDGE;
}

// direct scatter: one 8-B random write per edge (col + val packed)
__global__ __launch_bounds__(BLK) void scatter_kernel(
    const int* __restrict__ rows, const int* __restrict__ cols,
    const float* __restrict__ vals, int* __restrict__ cursor,
    int2* __restrict__ cmeta) {
    int e = blockIdx.x * BLK + threadIdx.x;
    if (e >= NEDGE) return;
    int k = e / NNZ_;
    int pos = atomicAdd(&cursor[k * N_ + rows[e]], 1);
    cmeta[pos] = make_int2(cols[e], __float_as_int(vals[e]));
}

// ---------------- iteration kernels ----------------

// Accumulate one CSR row [beg,end): bf16 gather (ushort4 = 128B/row = 1 line),
// fp32 FMA. Meta (int2) loaded lane-parallel, broadcast via __shfl.
// Gathers issued in batches of 4 (iters padded; inactive lanes hold c=0,v=0,
// padded gathers hit X row 0 and contribute 0) -> 4x MLP.
__device__ __forceinline__ void row_accum_bf(
    const int2* __restrict__ cmeta, const ushort4* __restrict__ Xb,
    int beg, int end, int lane, int sub, int q, float4& acc) {
    for (int ebase = beg; ebase < end; ebase += 64) {
        int n = end - ebase;             // wave-uniform
        if (n > 64) n = 64;
        int2 m_l = make_int2(0, 0);
        if (lane < n) m_l = cmeta[ebase + lane];
        int   c_l = m_l.x;
        float v_l = __int_as_float(m_l.y);
        int itersPad = ((n + 3) >> 2 + 0);
        itersPad = (itersPad + 3) & ~3;  // multiple of 4, <= 16
        for (int it0 = 0; it0 < itersPad; it0 += 4) {
            float   vv[4];
            ushort4 xx[4];
            #pragma unroll
            for (int u = 0; u < 4; ++u) {
                int j = 4 * (it0 + u) + sub;      // < 64
                int   c = __shfl(c_l, j, 64);
                vv[u]   = __shfl(v_l, j, 64);
                xx[u]   = Xb[c * (FEAT_ / 4) + q];
            }
            #pragma unroll
            for (int u = 0; u < 4; ++u) {
                acc.x += vv[u] * bf2f(xx[u].x);
                acc.y += vv[u] * bf2f(xx[u].y);
                acc.z += vv[u] * bf2f(xx[u].z);
                acc.w += vv[u] * bf2f(xx[u].w);
            }
        }
    }
}

__device__ __forceinline__ void butterfly4(float4& a) {
    #pragma unroll
    for (int m = 16; m <= 32; m <<= 1) {
        a.x += __shfl_xor(a.x, m, 64);
        a.y += __shfl_xor(a.y, m, 64);
        a.z += __shfl_xor(a.z, m, 64);
        a.w += __shfl_xor(a.w, m, 64);
    }
}

// wave per R_SP contiguous (k,row) CSR rows; acc = (W_k @ X)[row]; fused
// v-update in bf16 state V_bf. FIRST: Y=0, X=F_bf.
template <bool FIRST>
__global__ __launch_bounds__(BLK) void spmm_fused_kernel(
    const int* __restrict__ offs, const int2* __restrict__ cmeta,
    const unsigned short* __restrict__ Xb,
    const float* __restrict__ d, unsigned short* __restrict__ V_bf) {
    int wave = (blockIdx.x * BLK + threadIdx.x) >> 6;
    int lane = threadIdx.x & 63;
    int sub  = lane >> 4, q = lane & 15;
    int base = wave * R_SP;
    if (base >= KN) return;
    int off_l = 0;
    if (lane <= R_SP) {
        int i = base + lane;
        if (i > KN) i = KN;
        off_l = offs[i];
    }
    const ushort4* X4 = (const ushort4*)Xb;
    ushort4* V4 = (ushort4*)V_bf;
    for (int r = 0; r < R_SP; ++r) {
        int w = base + r;
        if (w >= KN) break;
        int beg = __shfl(off_l, r, 64);
        int end = __shfl(off_l, r + 1, 64);
        float4 acc = {0.f, 0.f, 0.f, 0.f};
        row_accum_bf(cmeta, X4, beg, end, lane, sub, q, acc);
        butterfly4(acc);                 // all lanes hold row sums
        if (sub == 0) {
            int k   = w / N_;
            int row = w - k * N_;
            int idx4 = w * (FEAT_ / 4) + q;
            float thr = c_nu[k] * d[row];
            float4 y;
            if (FIRST) {
                y = make_float4(0.f, 0.f, 0.f, 0.f);
            } else {
                ushort4 vp = V4[idx4];   // v_{t-1}
                y.x = acc.x + bf2f(vp.x); y.y = acc.y + bf2f(vp.y);
                y.z = acc.z + bf2f(vp.z); y.w = acc.w + bf2f(vp.w);
            }
            ushort4 o;
            o.x = f2bf(y.x - softf(acc.x + y.x, thr));
            o.y = f2bf(y.y - softf(acc.y + y.y, thr));
            o.z = f2bf(y.z - softf(acc.z + y.z, thr));
            o.w = f2bf(y.w - softf(acc.w + y.w, thr));
            V4[idx4] = o;                // v_t
        }
    }
}

// wave per R_WT contiguous node rows: acc = sum_k (W_k @ v_k)[row];
// U = (dm*F - acc)/(dm+1), stored fp32 (d_out) + bf16 (gather copy)
__global__ __launch_bounds__(BLK) void wtv_u_kernel(
    const int* __restrict__ offs, const int2* __restrict__ cmeta,
    const unsigned short* __restrict__ V_bf,
    const float* __restrict__ F, const float* __restrict__ dm,
    float* __restrict__ U, unsigned short* __restrict__ U_bf) {
    int wave = (blockIdx.x * BLK + threadIdx.x) >> 6;
    int lane = threadIdx.x & 63;
    int sub  = lane >> 4, q = lane & 15;
    int base = wave * R_WT;
    if (base >= N_) return;
    int off_l[K_];
    #pragma unroll
    for (int k = 0; k < K_; ++k) {
        int i = base + lane;
        if (i > N_) i = N_;
        off_l[k] = (lane <= R_WT) ? offs[k * N_ + i] : 0;
    }
    for (int r = 0; r < R_WT; ++r) {
        int w = base + r;
        if (w >= N_) break;
        float4 acc = {0.f, 0.f, 0.f, 0.f};
        #pragma unroll
        for (int k = 0; k < K_; ++k) {
            int beg = __shfl(off_l[k], r, 64);
            int end = __shfl(off_l[k], r + 1, 64);
            row_accum_bf(cmeta, (const ushort4*)(V_bf + (size_t)k * NF),
                         beg, end, lane, sub, q, acc);
        }
        butterfly4(acc);
        if (sub == 0) {
            int idx4 = w * (FEAT_ / 4) + q;
            float dmv = dm[w];
            float r2 = 1.0f / (dmv + 1.0f);
            float4 f = ((const float4*)F)[idx4];
            float4 o;
            o.x = (dmv * f.x - acc.x) * r2; o.y = (dmv * f.y - acc.y) * r2;
            o.z = (dmv * f.z - acc.z) * r2; o.w = (dmv * f.w - acc.w) * r2;
            ((float4*)U)[idx4] = o;
            ushort4 ob;
            ob.x = f2bf(o.x); ob.y = f2bf(o.y);
            ob.z = f2bf(o.z); ob.w = f2bf(o.w);
            ((ushort4*)U_bf)[idx4] = ob;
        }
    }
}

extern "C" void kernel_launch(void* const* d_in, const int* in_sizes, int n_in,
                              void* d_out, int out_size, void* d_ws, size_t ws_size,
                              hipStream_t stream) {
    const float* F      = (const float*)d_in[0];
    const int*   w_rows = (const int*)d_in[1];
    const int*   w_cols = (const int*)d_in[2];
    const float* w_vals = (const float*)d_in[3];
    const float* d      = (const float*)d_in[4];
    const float* mask   = (const float*)d_in[5];
    float* U = (float*)d_out;

    // workspace layout (~27 MB); cmeta first for 8/16-B alignment
    int2* cmeta          = (int2*)d_ws;                    // NEDGE int2
    unsigned short* V_bf = (unsigned short*)(cmeta + NEDGE);  // KN*FEAT us
    unsigned short* U_bf = V_bf + (size_t)KN * FEAT_;      // NF us
    unsigned short* F_bf = U_bf + NF;                      // NF us
    float* dm     = (float*)(F_bf + NF);                   // N
    int*   cnt    = (int*)(dm + N_);                       // KN
    int*   loc    = cnt + KN;                              // KN
    int*   bsum   = loc + KN;                              // pad 512
    int*   offs   = bsum + 512;                            // KN+1
    int*   cursor = offs + KN + 1;                         // KN

    const int gEdge = NEDGE / BLK;                // 5000
    const int gNF4  = (NF / 4) / BLK;             // 1250

    // ---- CSR build + precompute ----
    hipMemsetAsync(cnt, 0, (size_t)KN * 4, stream);
    precompute_kernel<<<gNF4, BLK, 0, stream>>>(F, d, mask, dm, F_bf);
    hist_kernel<<<gEdge, BLK, 0, stream>>>(w_rows, cnt);
    scan1_kernel<<<NSB, 256, 0, stream>>>(cnt, loc, bsum);
    scan2_kernel<<<1, 512, 0, stream>>>(bsum);
    scan3_kernel<<<NSB, 256, 0, stream>>>(loc, bsum, offs, cursor);
    scatter_kernel<<<gEdge, BLK, 0, stream>>>(w_rows, w_cols, w_vals,
                                              cursor, cmeta);

    // ---- iterations ----
    spmm_fused_kernel<true><<<NB_SP, BLK, 0, stream>>>(offs, cmeta, F_bf, d, V_bf);
    for (int it = 0; it < NITER; ++it) {
        wtv_u_kernel<<<NB_WT, BLK, 0, stream>>>(offs, cmeta, V_bf,
                                                F, dm, U, U_bf);
        if (it < NITER - 1)
            spmm_fused_kernel<false><<<NB_SP, BLK, 0, stream>>>(offs, cmeta,
                                                                U_bf, d, V_bf);
    }
}

// Round 8
// 967.515 us; speedup vs baseline: 1.4541x; 1.0875x over previous
//
#include <hip/hip_runtime.h>

// NodeDenoisingADMM: N=20000, FEAT=64, K=4, NNZ=320000, NU=2.0, GAMMA=1.0, J=3
// 14 scan iterations, output = final U (N,FEAT) fp32.
//
// State reduction (GAMMA=1): carried state is v alone.
//   S_t = W_k @ U_t ; Y_t = S_t + v_{t-1} ; Z_t = soft(S_t + Y_t, nu_k d)
//   v_t = Y_t - Z_t ; U_{t+1} = (dm*F - sum_k W_k v_k)/(dm+1), dm = d*mask^2
//
// Node-major CSR: rowid = n*K + k, stored col' = k*N + col.
//  - wtv: edges of node n over ALL graphs are contiguous -> single flat
//    segment (~64 edges), gathered straight from V_bf[col'] (layout [k][n]).
//  - spmm: per-(n,k) row; shared-X gather recovered by adjusting the base
//    pointer by -k*N (scalar per row, free); pad col = k*N stays in bounds.
// Gather operands are bf16; meta packed int2{col', val}; gathers issued in
// batches (4 spmm / 8 wtv) for memory-level parallelism.

constexpr int N_    = 20000;
constexpr int FEAT_ = 64;
constexpr int K_    = 4;
constexpr int NNZ_  = 320000;
constexpr int NF    = N_ * FEAT_;     // 1,280,000
constexpr int KN    = K_ * N_;        // 80,000 CSR rows
constexpr int NEDGE = K_ * NNZ_;      // 1,280,000
constexpr int NITER = 14;
constexpr int BLK   = 256;
constexpr int NSB   = (KN + 255) / 256;  // 313 scan blocks

constexpr int R_SP  = 10;                          // CSR rows/wave, spmm
constexpr int NB_SP = ((KN + R_SP - 1) / R_SP + 3) / 4;   // 2000 blocks
constexpr int R_WT  = 4;                           // nodes/wave, wtv
constexpr int NB_WT = ((N_ + R_WT - 1) / R_WT + 3) / 4;   // 1250 blocks

__constant__ float c_nu[4] = {0.0f, 2.0f, 0.5f, 0.125f};

__device__ __forceinline__ float softf(float x, float t) {
    float a = fabsf(x) - t;
    a = a > 0.0f ? a : 0.0f;
    return copysignf(a, x);
}

__device__ __forceinline__ float bf2f(unsigned short u) {
    union { unsigned int i; float f; } x;
    x.i = ((unsigned int)u) << 16;
    return x.f;
}
__device__ __forceinline__ unsigned short f2bf(float f) {   // RNE
    union { float f; unsigned int i; } x;
    x.f = f;
    unsigned int r = x.i + 0x7FFFu + ((x.i >> 16) & 1u);
    return (unsigned short)(r >> 16);
}

// ---------------- CSR build + precompute ----------------

// dm[n] = d*mask^2 ; F_bf = bf16(F)
__global__ __launch_bounds__(BLK) void precompute_kernel(
    const float* __restrict__ F, const float* __restrict__ d,
    const float* __restrict__ mask, float* __restrict__ dm,
    unsigned short* __restrict__ F_bf) {
    int i = blockIdx.x * BLK + threadIdx.x;       // over NF/4
    if (i >= NF / 4) return;
    float4 f = ((const float4*)F)[i];
    ushort4 o;
    o.x = f2bf(f.x); o.y = f2bf(f.y); o.z = f2bf(f.z); o.w = f2bf(f.w);
    ((ushort4*)F_bf)[i] = o;
    if ((i & (FEAT_ / 4 - 1)) == 0) {
        int n = i / (FEAT_ / 4);
        dm[n] = d[n] * mask[n] * mask[n];
    }
}

// rowid = rows[e]*K + k
__global__ __launch_bounds__(BLK) void hist_kernel(
    const int* __restrict__ rows, int* __restrict__ cnt) {
    int e = blockIdx.x * BLK + threadIdx.x;
    if (e >= NEDGE) return;
    int k = e / NNZ_;
    atomicAdd(&cnt[rows[e] * K_ + k], 1);
}

__global__ __launch_bounds__(256) void scan1_kernel(
    const int* __restrict__ cnt, int* __restrict__ loc,
    int* __restrict__ bsum) {
    int i = blockIdx.x * 256 + threadIdx.x;
    int x = (i < KN) ? cnt[i] : 0;
    int lane = threadIdx.x & 63, wid = threadIdx.x >> 6;
    int v = x;
    #pragma unroll
    for (int off = 1; off < 64; off <<= 1) {
        int t = __shfl_up(v, off, 64);
        if (lane >= off) v += t;
    }
    __shared__ int ws[4];
    if (lane == 63) ws[wid] = v;
    __syncthreads();
    int add = 0;
    for (int u = 0; u < wid; ++u) add += ws[u];
    v += add;
    if (i < KN) loc[i] = v - x;
    if (threadIdx.x == 255) bsum[blockIdx.x] = v;
}

__global__ __launch_bounds__(512) void scan2_kernel(int* __restrict__ bsum) {
    int tid = threadIdx.x;
    int x = (tid < NSB) ? bsum[tid] : 0;
    int lane = tid & 63, wid = tid >> 6;
    int v = x;
    #pragma unroll
    for (int off = 1; off < 64; off <<= 1) {
        int t = __shfl_up(v, off, 64);
        if (lane >= off) v += t;
    }
    __shared__ int ws[8];
    if (lane == 63) ws[wid] = v;
    __syncthreads();
    int add = 0;
    for (int u = 0; u < wid; ++u) add += ws[u];
    v += add;
    if (tid < NSB) bsum[tid] = v - x;
}

__global__ __launch_bounds__(256) void scan3_kernel(
    const int* __restrict__ loc, const int* __restrict__ bsum,
    int* __restrict__ offs, int* __restrict__ cursor) {
    int i = blockIdx.x * 256 + threadIdx.x;
    if (i < KN) {
        int v = loc[i] + bsum[blockIdx.x];
        offs[i] = v;
        cursor[i] = v;
    }
    if (i == 0) offs[KN] = NEDGE;
}

// direct scatter: one 8-B random write per edge; stores col' = k*N + col
__global__ __launch_bounds__(BLK) void scatter_kernel(
    const int* __restrict__ rows, const int* __restrict__ cols,
    const float* __restrict__ vals, int* __restrict__ cursor,
    int2* __restrict__ cmeta) {
    int e = blockIdx.x * BLK + threadIdx.x;
    if (e >= NEDGE) return;
    int k = e / NNZ_;
    int pos = atomicAdd(&cursor[rows[e] * K_ + k], 1);
    cmeta[pos] = make_int2(k * N_ + cols[e], __float_as_int(vals[e]));
}

// ---------------- iteration kernels ----------------

// Accumulate edges [beg,end) into acc. bf16 gather (ushort4, 128B/row-read),
// fp32 FMA. Meta loaded lane-parallel per 64-edge chunk, broadcast via __shfl.
// Gathers issued in batches of BATCH for MLP. Pad column = padc (in-bounds).
template <int BATCH>
__device__ __forceinline__ void row_accum_bf(
    const int2* __restrict__ cmeta, const ushort4* __restrict__ Xb,
    int beg, int end, int lane, int sub, int q, int padc, float4& acc) {
    for (int ebase = beg; ebase < end; ebase += 64) {
        int n = end - ebase;             // wave-uniform
        if (n > 64) n = 64;
        int   c_l = padc;
        float v_l = 0.0f;
        if (lane < n) {
            int2 m = cmeta[ebase + lane];
            c_l = m.x;
            v_l = __int_as_float(m.y);
        }
        int iters = (n + 3) >> 2;
        int itersPad = (iters + BATCH - 1) & ~(BATCH - 1);  // <= 16
        for (int it0 = 0; it0 < itersPad; it0 += BATCH) {
            float   vv[BATCH];
            ushort4 xx[BATCH];
            #pragma unroll
            for (int u = 0; u < BATCH; ++u) {
                int j = 4 * (it0 + u) + sub;      // < 64
                int   c = __shfl(c_l, j, 64);
                vv[u]   = __shfl(v_l, j, 64);
                xx[u]   = Xb[c * (FEAT_ / 4) + q];
            }
            #pragma unroll
            for (int u = 0; u < BATCH; ++u) {
                acc.x += vv[u] * bf2f(xx[u].x);
                acc.y += vv[u] * bf2f(xx[u].y);
                acc.z += vv[u] * bf2f(xx[u].z);
                acc.w += vv[u] * bf2f(xx[u].w);
            }
        }
    }
}

__device__ __forceinline__ void butterfly4(float4& a) {
    #pragma unroll
    for (int m = 16; m <= 32; m <<= 1) {
        a.x += __shfl_xor(a.x, m, 64);
        a.y += __shfl_xor(a.y, m, 64);
        a.z += __shfl_xor(a.z, m, 64);
        a.w += __shfl_xor(a.w, m, 64);
    }
}

// wave per R_SP contiguous CSR rows (rowid = n*K+k); acc = (W_k @ X)[n];
// fused v-update into bf16 V_bf (layout [k][n]). FIRST: Y=0, X=F_bf.
template <bool FIRST>
__global__ __launch_bounds__(BLK) void spmm_fused_kernel(
    const int* __restrict__ offs, const int2* __restrict__ cmeta,
    const unsigned short* __restrict__ Xb,
    const float* __restrict__ d, unsigned short* __restrict__ V_bf) {
    int wave = (blockIdx.x * BLK + threadIdx.x) >> 6;
    int lane = threadIdx.x & 63;
    int sub  = lane >> 4, q = lane & 15;
    int base = wave * R_SP;
    if (base >= KN) return;
    int off_l = 0;
    if (lane <= R_SP) {
        int i = base + lane;
        if (i > KN) i = KN;
        off_l = offs[i];
    }
    const ushort4* X4 = (const ushort4*)Xb;
    ushort4* V4 = (ushort4*)V_bf;
    for (int r = 0; r < R_SP; ++r) {
        int w = base + r;                // rowid = n*K + k
        if (w >= KN) break;
        int k = w & (K_ - 1);
        int n = w >> 2;
        int beg = __shfl(off_l, r, 64);
        int end = __shfl(off_l, r + 1, 64);
        // col' = k*N + col; recover shared-X indexing via base adjust (free)
        const ushort4* X4m = X4 - (size_t)k * N_ * (FEAT_ / 4);
        float4 acc = {0.f, 0.f, 0.f, 0.f};
        row_accum_bf<4>(cmeta, X4m, beg, end, lane, sub, q, k * N_, acc);
        butterfly4(acc);                 // all lanes hold row sums
        if (sub == 0) {
            int idx4 = (k * N_ + n) * (FEAT_ / 4) + q;
            float thr = c_nu[k] * d[n];
            float4 y;
            if (FIRST) {
                y = make_float4(0.f, 0.f, 0.f, 0.f);
            } else {
                ushort4 vp = V4[idx4];   // v_{t-1}
                y.x = acc.x + bf2f(vp.x); y.y = acc.y + bf2f(vp.y);
                y.z = acc.z + bf2f(vp.z); y.w = acc.w + bf2f(vp.w);
            }
            ushort4 o;
            o.x = f2bf(y.x - softf(acc.x + y.x, thr));
            o.y = f2bf(y.y - softf(acc.y + y.y, thr));
            o.z = f2bf(y.z - softf(acc.z + y.z, thr));
            o.w = f2bf(y.w - softf(acc.w + y.w, thr));
            V4[idx4] = o;                // v_t
        }
    }
}

// wave per R_WT nodes: node n's edges over ALL k are contiguous
// [offs[4n], offs[4n+4]) with col' indexing V_bf directly -> single flat
// segment, no k-structure. U = (dm*F - acc)/(dm+1), fp32 + bf16 copies.
__global__ __launch_bounds__(BLK) void wtv_u_kernel(
    const int* __restrict__ offs, const int2* __restrict__ cmeta,
    const unsigned short* __restrict__ V_bf,
    const float* __restrict__ F, const float* __restrict__ dm,
    float* __restrict__ U, unsigned short* __restrict__ U_bf) {
    int wave = (blockIdx.x * BLK + threadIdx.x) >> 6;
    int lane = threadIdx.x & 63;
    int sub  = lane >> 4, q = lane & 15;
    int base = wave * R_WT;
    if (base >= N_) return;
    int off_l = 0;
    if (lane <= K_ * R_WT) {             // 17 offsets
        int i = K_ * base + lane;
        if (i > KN) i = KN;
        off_l = offs[i];
    }
    const ushort4* V4 = (const ushort4*)V_bf;
    for (int r = 0; r < R_WT; ++r) {
        int n = base + r;
        if (n >= N_) break;
        int beg = __shfl(off_l, K_ * r, 64);
        int end = __shfl(off_l, K_ * r + K_, 64);
        float4 acc = {0.f, 0.f, 0.f, 0.f};
        row_accum_bf<8>(cmeta, V4, beg, end, lane, sub, q, 0, acc);
        butterfly4(acc);
        if (sub == 0) {
            int idx4 = n * (FEAT_ / 4) + q;
            float dmv = dm[n];
            float r2 = 1.0f / (dmv + 1.0f);
            float4 f = ((const float4*)F)[idx4];
            float4 o;
            o.x = (dmv * f.x - acc.x) * r2; o.y = (dmv * f.y - acc.y) * r2;
            o.z = (dmv * f.z - acc.z) * r2; o.w = (dmv * f.w - acc.w) * r2;
            ((float4*)U)[idx4] = o;
            ushort4 ob;
            ob.x = f2bf(o.x); ob.y = f2bf(o.y);
            ob.z = f2bf(o.z); ob.w = f2bf(o.w);
            ((ushort4*)U_bf)[idx4] = ob;
        }
    }
}

extern "C" void kernel_launch(void* const* d_in, const int* in_sizes, int n_in,
                              void* d_out, int out_size, void* d_ws, size_t ws_size,
                              hipStream_t stream) {
    const float* F      = (const float*)d_in[0];
    const int*   w_rows = (const int*)d_in[1];
    const int*   w_cols = (const int*)d_in[2];
    const float* w_vals = (const float*)d_in[3];
    const float* d      = (const float*)d_in[4];
    const float* mask   = (const float*)d_in[5];
    float* U = (float*)d_out;

    // workspace layout (~27 MB); cmeta first for 8/16-B alignment
    int2* cmeta          = (int2*)d_ws;                       // NEDGE int2
    unsigned short* V_bf = (unsigned short*)(cmeta + NEDGE);  // KN*FEAT us
    unsigned short* U_bf = V_bf + (size_t)KN * FEAT_;         // NF us
    unsigned short* F_bf = U_bf + NF;                         // NF us
    float* dm     = (float*)(F_bf + NF);                      // N
    int*   cnt    = (int*)(dm + N_);                          // KN
    int*   loc    = cnt + KN;                                 // KN
    int*   bsum   = loc + KN;                                 // pad 512
    int*   offs   = bsum + 512;                               // KN+1
    int*   cursor = offs + KN + 1;                            // KN

    const int gEdge = NEDGE / BLK;                // 5000
    const int gNF4  = (NF / 4) / BLK;             // 1250

    // ---- CSR build + precompute ----
    hipMemsetAsync(cnt, 0, (size_t)KN * 4, stream);
    precompute_kernel<<<gNF4, BLK, 0, stream>>>(F, d, mask, dm, F_bf);
    hist_kernel<<<gEdge, BLK, 0, stream>>>(w_rows, cnt);
    scan1_kernel<<<NSB, 256, 0, stream>>>(cnt, loc, bsum);
    scan2_kernel<<<1, 512, 0, stream>>>(bsum);
    scan3_kernel<<<NSB, 256, 0, stream>>>(loc, bsum, offs, cursor);
    scatter_kernel<<<gEdge, BLK, 0, stream>>>(w_rows, w_cols, w_vals,
                                              cursor, cmeta);

    // ---- iterations ----
    spmm_fused_kernel<true><<<NB_SP, BLK, 0, stream>>>(offs, cmeta, F_bf, d, V_bf);
    for (int it = 0; it < NITER; ++it) {
        wtv_u_kernel<<<NB_WT, BLK, 0, stream>>>(offs, cmeta, V_bf,
                                                F, dm, U, U_bf);
        if (it < NITER - 1)
            spmm_fused_kernel<false><<<NB_SP, BLK, 0, stream>>>(offs, cmeta,
                                                                U_bf, d, V_bf);
    }
}